// Round 17
// baseline (288.997 us; speedup 1.0000x reference)
//
#include <hip/hip_runtime.h>
#include <hip/hip_bf16.h>
#include <math.h>

#define Nn 20000
#define En 320000
#define Gn 16
#define DINn 1280
#define Hn 256
#define Cn 500
#define EPSn 1e-5f
#define BNB 1024
#define SCB 256
#define SNB ((Nn + SCB - 1) / SCB)   // 79 scan blocks

typedef __attribute__((ext_vector_type(8))) short bf16x8;
typedef __attribute__((ext_vector_type(4))) float f32x4;

__device__ __forceinline__ float b2f(ushort u) {
    return __uint_as_float(((unsigned int)u) << 16);
}
__device__ __forceinline__ ushort f2b(float f) {
    __hip_bfloat16 h = __float2bfloat16(f);
    return *reinterpret_cast<ushort*>(&h);
}

#define GLOAD16(g, l) __builtin_amdgcn_global_load_lds( \
    (const __attribute__((address_space(1))) unsigned int*)(g), \
    (__attribute__((address_space(3))) unsigned int*)(l), 16, 0, 0)

// ---------------- degree+count / CSR build (fused) ----------------

__global__ void k_degcnt(const int* col, const float* ew, float* deg, int* counts) {
    int e = blockIdx.x * blockDim.x + threadIdx.x;
    if (e < En) {
        int c = col[e];
        atomicAdd(&deg[c], ew[e]);
        atomicAdd(&counts[c], 1);
    }
}

__global__ void k_dinv(const float* deg, float* dinv, float* dinv2) {
    int i = blockIdx.x * blockDim.x + threadIdx.x;
    if (i < Nn) {
        float d = deg[i] + 1.0f;
        float r = rsqrtf(d);
        dinv[i] = r;
        dinv2[i] = 1.0f / d;
    }
}

// ---------------- multi-block exclusive scan ----------------

__global__ __launch_bounds__(SCB) void k_scanA(const int* __restrict__ counts,
                                               int* __restrict__ excl,
                                               int* __restrict__ blocksum) {
    __shared__ int sd[SCB];
    int t = threadIdx.x, b = blockIdx.x;
    int i = b * SCB + t;
    int v = (i < Nn) ? counts[i] : 0;
    sd[t] = v;
    __syncthreads();
    #pragma unroll
    for (int o = 1; o < SCB; o <<= 1) {
        int tv = (t >= o) ? sd[t - o] : 0;
        __syncthreads();
        sd[t] += tv;
        __syncthreads();
    }
    if (i < Nn) excl[i] = sd[t] - v;
    if (t == SCB - 1) blocksum[b] = sd[t];
}

__global__ __launch_bounds__(128) void k_scanB(const int* __restrict__ blocksum,
                                               int* __restrict__ blockoff,
                                               int* __restrict__ offsets) {
    __shared__ int sd[128];
    int t = threadIdx.x;
    int v = (t < SNB) ? blocksum[t] : 0;
    sd[t] = v;
    __syncthreads();
    #pragma unroll
    for (int o = 1; o < 128; o <<= 1) {
        int tv = (t >= o) ? sd[t - o] : 0;
        __syncthreads();
        sd[t] += tv;
        __syncthreads();
    }
    if (t < SNB) blockoff[t] = sd[t] - v;
    if (t == SNB - 1) offsets[Nn] = sd[t];
}

__global__ __launch_bounds__(SCB) void k_scanC(const int* __restrict__ excl,
                                               const int* __restrict__ blockoff,
                                               int* __restrict__ offsets,
                                               int* __restrict__ cursor) {
    int b = blockIdx.x;
    int i = b * SCB + threadIdx.x;
    if (i < Nn) {
        int o = excl[i] + blockoff[b];
        offsets[i] = o;
        cursor[i] = o;
    }
}

// fill with fused norm computation: csr_w = dinv[r]*ew*dinv[c]
__global__ void k_fill2(const int* row, const int* col, const float* ew,
                        const float* dinv, int* cursor,
                        int* csr_row, float* csr_w) {
    int e = blockIdx.x * blockDim.x + threadIdx.x;
    if (e < En) {
        int r = row[e], c = col[e];
        int p = atomicAdd(&cursor[c], 1);
        csr_row[p] = r;
        csr_w[p] = dinv[r] * ew[e] * dinv[c];
    }
}

// ---------------- group bounds from sorted batch ----------------

__global__ void k_gbounds(const int* __restrict__ batch, int* __restrict__ gstart) {
    int i = blockIdx.x * blockDim.x + threadIdx.x;
    if (i >= Nn) return;
    int b = batch[i];
    if (i == 0) {
        for (int g = 0; g <= b; g++) gstart[g] = 0;
    } else {
        int pb = batch[i - 1];
        for (int g = pb + 1; g <= b; g++) gstart[g] = i;
    }
    if (i == Nn - 1) {
        for (int g = b + 1; g <= Gn; g++) gstart[g] = Nn;
    }
}

// ---------------- plain weight transpose (W1) ----------------

__global__ __launch_bounds__(256) void k_wt(const float* __restrict__ W,
                                            ushort* __restrict__ WT, int K) {
    __shared__ float tile[32][33];
    int k0 = blockIdx.x * 32, n0 = blockIdx.y * 32;
    int tx = threadIdx.x, ty = threadIdx.y;   // (32, 8)
    #pragma unroll
    for (int i = 0; i < 32; i += 8)
        tile[ty + i][tx] = W[(size_t)(k0 + ty + i) * Hn + n0 + tx];
    __syncthreads();
    #pragma unroll
    for (int i = 0; i < 32; i += 8)
        WT[(size_t)(n0 + ty + i) * K + k0 + tx] = f2b(tile[tx][ty + i]);
}

// ---------------- affine-folded weight transform (W2/W3) ----------------

__global__ __launch_bounds__(256) void k_wtb(const float* __restrict__ W,
                                             const float* __restrict__ scaleA,
                                             const float* __restrict__ shiftA,
                                             ushort* __restrict__ WT,
                                             float* __restrict__ bv) {
    __shared__ float tile[32][33];
    int k0 = blockIdx.x * 32, n0 = blockIdx.y * 32;
    int tx = threadIdx.x, ty = threadIdx.y;   // (32, 8)
    #pragma unroll
    for (int i = 0; i < 32; i += 8)
        tile[ty + i][tx] = W[(size_t)(k0 + ty + i) * Hn + n0 + tx];
    __syncthreads();
    float sc = scaleA[k0 + tx], sh = shiftA[k0 + tx];
    #pragma unroll
    for (int i = 0; i < 32; i += 8) {
        float w = tile[tx][ty + i];   // k = k0+tx, n = n0+ty+i
        WT[(size_t)(n0 + ty + i) * Hn + k0 + tx] = f2b(w * sc);
        float pb = w * sh;
        #pragma unroll
        for (int o = 16; o > 0; o >>= 1) pb += __shfl_down(pb, o, 32);
        if (tx == 0) atomicAdd(&bv[n0 + ty + i], pb);
    }
}

// ---------------- GEMM tiles: 64x64, wave tile 32x32, 2-phase dbuf ----------------
// XCD swizzle: all 4 N-quarters of an A-panel share ids == r (mod 8) -> same XCD.

#define GBM 64
#define GBN 64
#define GBK 64

__global__ __launch_bounds__(256) void k_gemm_f32a(
    const float* __restrict__ A, const ushort* __restrict__ BT,
    ushort* __restrict__ C, int M, int K, int NBL)
{
    __shared__ ushort Asl[2][GBM][GBK];   // 16 KB
    __shared__ ushort Bsl[2][GBN][GBK];   // 16 KB
    const int id = blockIdx.x;
    const int k8 = id >> 3;
    const int r8 = id & 7;
    const int p = (k8 >> 2) * 8 + r8;   // A-panel
    const int bnk = k8 & 3;             // N-quarter
    if (p >= NBL) return;
    const int bm = p * GBM;
    const int bn = bnk * GBN;
    const int tid = threadIdx.x;
    const int lane = tid & 63;
    const int wid = tid >> 6;
    const int wm = wid >> 1, wn = wid & 1;   // wave tile 32 x 32
    const int l15 = lane & 15, l16 = lane >> 4;

    // B staging (global_load_lds, pre-swizzled source)
    const int lrow = lane >> 3;
    const int lcolb = 16 * ((lane & 7) ^ lrow);
    // A staging (reg): thread -> row tid>>2, 16 f32 at col (tid&3)*16
    const int arow = tid >> 2;
    const int acol = (tid & 3) * 16;
    int agrow = bm + arow; if (agrow >= M) agrow = M - 1;
    const int awoff0 = (acol * 2) ^ ((arow & 7) << 4);
    const int awoff1 = (acol * 2 + 16) ^ ((arow & 7) << 4);

    f32x4 acc[2][2] = {};
    const int nt = K / GBK;

    float4 fa0, fa1, fa2, fa3;
    auto LOADA = [&](int t) {
        const float4* ap = reinterpret_cast<const float4*>(
            &A[(size_t)agrow * K + t * GBK + acol]);
        fa0 = ap[0]; fa1 = ap[1]; fa2 = ap[2]; fa3 = ap[3];
    };
    auto WRITEA = [&](int buf) {
        ushort t16[16];
        t16[0]  = f2b(fa0.x); t16[1]  = f2b(fa0.y); t16[2]  = f2b(fa0.z); t16[3]  = f2b(fa0.w);
        t16[4]  = f2b(fa1.x); t16[5]  = f2b(fa1.y); t16[6]  = f2b(fa1.z); t16[7]  = f2b(fa1.w);
        t16[8]  = f2b(fa2.x); t16[9]  = f2b(fa2.y); t16[10] = f2b(fa2.z); t16[11] = f2b(fa2.w);
        t16[12] = f2b(fa3.x); t16[13] = f2b(fa3.y); t16[14] = f2b(fa3.z); t16[15] = f2b(fa3.w);
        char* base = (char*)&Asl[buf][arow][0];
        *reinterpret_cast<uint4*>(base + awoff0) = *reinterpret_cast<uint4*>(&t16[0]);
        *reinterpret_cast<uint4*>(base + awoff1) = *reinterpret_cast<uint4*>(&t16[8]);
    };
    auto STAGEB = [&](int buf, int t) {
        const int k0 = t * GBK;
        #pragma unroll
        for (int c = 0; c < 2; c++) {
            int chunk = wid * 2 + c;        // 8 chunks over B (64 rows)
            int grow = bn + chunk * 8 + lrow;
            const char* src = (const char*)&BT[(size_t)grow * K + k0] + lcolb;
            GLOAD16(src, &Bsl[buf][chunk * 8][0]);
        }
    };

    LOADA(0);
    STAGEB(0, 0);
    WRITEA(0);
    __syncthreads();

    for (int t = 0; t < nt; t++) {
        const int cur = t & 1;
        if (t + 1 < nt) { LOADA(t + 1); STAGEB(cur ^ 1, t + 1); }
        #pragma unroll
        for (int ks = 0; ks < 2; ks++) {
            bf16x8 afr[2], bfr[2];
            #pragma unroll
            for (int i = 0; i < 2; i++) {
                int r = wm * 32 + i * 16 + l15;
                int cb = (ks * 64 + l16 * 16) ^ ((r & 7) << 4);
                afr[i] = *reinterpret_cast<const bf16x8*>((const char*)&Asl[cur][r][0] + cb);
            }
            #pragma unroll
            for (int j = 0; j < 2; j++) {
                int r = wn * 32 + j * 16 + l15;
                int cb = (ks * 64 + l16 * 16) ^ ((r & 7) << 4);
                bfr[j] = *reinterpret_cast<const bf16x8*>((const char*)&Bsl[cur][r][0] + cb);
            }
            #pragma unroll
            for (int i = 0; i < 2; i++)
                #pragma unroll
                for (int j = 0; j < 2; j++)
                    acc[i][j] = __builtin_amdgcn_mfma_f32_16x16x32_bf16(afr[i], bfr[j], acc[i][j], 0, 0, 0);
        }
        if (t + 1 < nt) WRITEA(cur ^ 1);
        __syncthreads();
    }

    #pragma unroll
    for (int i = 0; i < 2; i++) {
        #pragma unroll
        for (int r = 0; r < 4; r++) {
            int grow = bm + wm * 32 + i * 16 + l16 * 4 + r;
            if (grow < M) {
                #pragma unroll
                for (int j = 0; j < 2; j++)
                    C[(size_t)grow * Hn + bn + wn * 32 + j * 16 + l15] = f2b(acc[i][j][r]);
            }
        }
    }
}

__global__ __launch_bounds__(256) void k_gemm_bf(
    const ushort* __restrict__ A, const ushort* __restrict__ BT,
    ushort* __restrict__ C, int M, int K, int NBL)
{
    __shared__ ushort Asl[2][GBM][GBK];
    __shared__ ushort Bsl[2][GBN][GBK];
    const int id = blockIdx.x;
    const int k8 = id >> 3;
    const int r8 = id & 7;
    const int p = (k8 >> 2) * 8 + r8;
    const int bnk = k8 & 3;
    if (p >= NBL) return;
    const int bm = p * GBM;
    const int bn = bnk * GBN;
    const int tid = threadIdx.x;
    const int lane = tid & 63;
    const int wid = tid >> 6;
    const int wm = wid >> 1, wn = wid & 1;
    const int l15 = lane & 15, l16 = lane >> 4;

    const int lrow = lane >> 3;
    const int lcolb = 16 * ((lane & 7) ^ lrow);

    f32x4 acc[2][2] = {};
    const int nt = K / GBK;

    auto STAGE = [&](int buf, int t) {
        const int k0 = t * GBK;
        #pragma unroll
        for (int c = 0; c < 2; c++) {
            int chunk = wid * 2 + c;        // 8 chunks over A
            int grow = bm + chunk * 8 + lrow;
            if (grow >= M) grow = M - 1;
            const char* src = (const char*)&A[(size_t)grow * K + k0] + lcolb;
            GLOAD16(src, &Asl[buf][chunk * 8][0]);
        }
        #pragma unroll
        for (int c = 0; c < 2; c++) {
            int chunk = wid * 2 + c;        // 8 chunks over B
            int grow = bn + chunk * 8 + lrow;
            const char* src = (const char*)&BT[(size_t)grow * K + k0] + lcolb;
            GLOAD16(src, &Bsl[buf][chunk * 8][0]);
        }
    };

    STAGE(0, 0);
    __syncthreads();

    for (int t = 0; t < nt; t++) {
        const int cur = t & 1;
        if (t + 1 < nt) STAGE(cur ^ 1, t + 1);
        #pragma unroll
        for (int ks = 0; ks < 2; ks++) {
            bf16x8 afr[2], bfr[2];
            #pragma unroll
            for (int i = 0; i < 2; i++) {
                int r = wm * 32 + i * 16 + l15;
                int cb = (ks * 64 + l16 * 16) ^ ((r & 7) << 4);
                afr[i] = *reinterpret_cast<const bf16x8*>((const char*)&Asl[cur][r][0] + cb);
            }
            #pragma unroll
            for (int j = 0; j < 2; j++) {
                int r = wn * 32 + j * 16 + l15;
                int cb = (ks * 64 + l16 * 16) ^ ((r & 7) << 4);
                bfr[j] = *reinterpret_cast<const bf16x8*>((const char*)&Bsl[cur][r][0] + cb);
            }
            #pragma unroll
            for (int i = 0; i < 2; i++)
                #pragma unroll
                for (int j = 0; j < 2; j++)
                    acc[i][j] = __builtin_amdgcn_mfma_f32_16x16x32_bf16(afr[i], bfr[j], acc[i][j], 0, 0, 0);
        }
        __syncthreads();
    }

    #pragma unroll
    for (int i = 0; i < 2; i++) {
        #pragma unroll
        for (int r = 0; r < 4; r++) {
            int grow = bm + wm * 32 + i * 16 + l16 * 4 + r;
            if (grow < M) {
                #pragma unroll
                for (int j = 0; j < 2; j++)
                    C[(size_t)grow * Hn + bn + wn * 32 + j * 16 + l15] = f2b(acc[i][j][r]);
            }
        }
    }
}

// ---------------- aggregation: half-wave per node, 4-deep ILP gather ----------------

__device__ __forceinline__ void agg_accum(float* acc, float w, const uint4& v) {
    unsigned int u;
    u = v.x; acc[0] += w * b2f((ushort)u); acc[1] += w * b2f((ushort)(u >> 16));
    u = v.y; acc[2] += w * b2f((ushort)u); acc[3] += w * b2f((ushort)(u >> 16));
    u = v.z; acc[4] += w * b2f((ushort)u); acc[5] += w * b2f((ushort)(u >> 16));
    u = v.w; acc[6] += w * b2f((ushort)u); acc[7] += w * b2f((ushort)(u >> 16));
}

__global__ __launch_bounds__(256) void k_agg(const ushort* __restrict__ xw,
                                             const int* __restrict__ offsets,
                                             const int* __restrict__ csr_row,
                                             const float* __restrict__ csr_w,
                                             const float* __restrict__ dinv2,
                                             const float* __restrict__ bias,
                                             const float* __restrict__ bv,
                                             ushort* __restrict__ outp, int do_relu) {
    int node = blockIdx.x * 8 + (threadIdx.x >> 5);
    int l32 = threadIdx.x & 31;
    int s = offsets[node], e = offsets[node + 1];
    const uint4* xw4 = reinterpret_cast<const uint4*>(xw);

    float acc[8] = {};
    float wsum = 0.f;
    int k = s;
    for (; k + 4 <= e; k += 4) {
        int r0 = csr_row[k],     r1 = csr_row[k + 1];
        int r2 = csr_row[k + 2], r3 = csr_row[k + 3];
        float w0 = csr_w[k],     w1 = csr_w[k + 1];
        float w2 = csr_w[k + 2], w3 = csr_w[k + 3];
        uint4 v0 = xw4[(size_t)r0 * 32 + l32];
        uint4 v1 = xw4[(size_t)r1 * 32 + l32];
        uint4 v2 = xw4[(size_t)r2 * 32 + l32];
        uint4 v3 = xw4[(size_t)r3 * 32 + l32];
        wsum += (w0 + w1) + (w2 + w3);
        agg_accum(acc, w0, v0);
        agg_accum(acc, w1, v1);
        agg_accum(acc, w2, v2);
        agg_accum(acc, w3, v3);
    }
    for (; k < e; k++) {
        int r = csr_row[k];
        float w = csr_w[k];
        uint4 v = xw4[(size_t)r * 32 + l32];
        wsum += w;
        agg_accum(acc, w, v);
    }
    float d2 = dinv2[node];
    wsum += d2;
    uint4 vs = xw4[(size_t)node * 32 + l32];
    agg_accum(acc, d2, vs);

    const float4* bp = reinterpret_cast<const float4*>(&bias[l32 * 8]);
    float4 bb0 = bp[0], bb1 = bp[1];
    acc[0] += bb0.x; acc[1] += bb0.y; acc[2] += bb0.z; acc[3] += bb0.w;
    acc[4] += bb1.x; acc[5] += bb1.y; acc[6] += bb1.z; acc[7] += bb1.w;
    if (bv) {
        const float4* vp = reinterpret_cast<const float4*>(&bv[l32 * 8]);
        float4 bv0 = vp[0], bv1 = vp[1];
        acc[0] += wsum * bv0.x; acc[1] += wsum * bv0.y;
        acc[2] += wsum * bv0.z; acc[3] += wsum * bv0.w;
        acc[4] += wsum * bv1.x; acc[5] += wsum * bv1.y;
        acc[6] += wsum * bv1.z; acc[7] += wsum * bv1.w;
    }
    if (do_relu) {
        #pragma unroll
        for (int q = 0; q < 8; q++) acc[q] = fmaxf(acc[q], 0.f);
    }
    uint4 o;
    o.x = (unsigned int)f2b(acc[0]) | ((unsigned int)f2b(acc[1]) << 16);
    o.y = (unsigned int)f2b(acc[2]) | ((unsigned int)f2b(acc[3]) << 16);
    o.z = (unsigned int)f2b(acc[4]) | ((unsigned int)f2b(acc[5]) << 16);
    o.w = (unsigned int)f2b(acc[6]) | ((unsigned int)f2b(acc[7]) << 16);
    reinterpret_cast<uint4*>(outp)[(size_t)node * 32 + l32] = o;
}

// ---------------- batch-norm stats ----------------

__global__ __launch_bounds__(256) void k_bnpart(const ushort* __restrict__ h,
                                                float* __restrict__ partial) {
    int f = threadIdx.x;
    int blk = blockIdx.x;
    float s = 0.0f, ss = 0.0f;
    for (int i = blk; i < Nn; i += BNB) {
        float v = b2f(h[(size_t)i * Hn + f]);
        s += v;
        ss += v * v;
    }
    partial[(size_t)blk * 512 + f] = s;
    partial[(size_t)blk * 512 + 256 + f] = ss;
}

__global__ __launch_bounds__(256) void k_bnred(const float* __restrict__ partial,
                                               float* __restrict__ p2) {
    int f = threadIdx.x;
    int b = blockIdx.x;
    int b0 = b * 64;
    float s = 0.0f, ss = 0.0f;
    for (int j = 0; j < 64; j++) {
        const float* p = &partial[(size_t)(b0 + j) * 512];
        s += p[f];
        ss += p[256 + f];
    }
    p2[b * 512 + f] = s;
    p2[b * 512 + 256 + f] = ss;
}

__global__ void k_bnfinal2(const float* __restrict__ p2, const float* g, const float* be,
                           float* scaleA, float* shiftA) {
    int f = threadIdx.x;
    float s = 0.f, ss = 0.f;
    #pragma unroll
    for (int j = 0; j < 16; j++) {
        s += p2[j * 512 + f];
        ss += p2[j * 512 + 256 + f];
    }
    float mean = s / (float)Nn;
    float var = ss / (float)Nn - mean * mean;
    float a = g[f] * rsqrtf(var + EPSn);
    scaleA[f] = a;
    shiftA[f] = be[f] - mean * a;
}

// ---------------- pooling ----------------

#define PCH 32

__global__ __launch_bounds__(256) void k_pool2(const ushort* __restrict__ h,
                                               const int* __restrict__ gstart,
                                               const float* __restrict__ scaleA,
                                               const float* __restrict__ shiftA,
                                               float* __restrict__ pooled) {
    int g = blockIdx.x;
    int chunk = blockIdx.y;
    int f = threadIdx.x;
    int s = gstart[g], e = gstart[g + 1];
    int len = e - s;
    if (len <= 0) return;
    int per = (len + PCH - 1) / PCH;
    int cs = s + chunk * per;
    int ce = cs + per; if (ce > e) ce = e;
    if (cs >= ce) return;
    float sc = scaleA[f], sh = shiftA[f];
    float acc = 0.0f;
    for (int i = cs; i < ce; i++)
        acc += b2f(h[(size_t)i * Hn + f]) * sc + sh;
    atomicAdd(&pooled[g * Hn + f], acc);
}

// ---------------- head: fc1 partials (no atomics) + finish ----------------

__global__ __launch_bounds__(256) void k_head1part(const float* __restrict__ seq_emb,
                                                   const float* __restrict__ fc1_w,
                                                   float* __restrict__ hpart) {
    int g = blockIdx.x;
    int kc = blockIdx.y;
    int j = threadIdx.x;
    const float* se = &seq_emb[(size_t)g * DINn + kc * 128];
    const float* w = &fc1_w[(size_t)kc * 128 * Hn + j];
    float acc = 0.0f;
    #pragma unroll 8
    for (int k = 0; k < 128; k++)
        acc += se[k] * w[(size_t)k * Hn];
    hpart[((size_t)g * 10 + kc) * Hn + j] = acc;
}

__global__ __launch_bounds__(256) void k_head2f(const float* __restrict__ hpart,
                                                const float* __restrict__ fc1_b,
                                                const float* __restrict__ pooled,
                                                const int* __restrict__ gstart,
                                                const float* __restrict__ lin_w,
                                                const float* __restrict__ lin_b,
                                                float* __restrict__ out) {
    __shared__ float pf[Hn];
    int g = blockIdx.x;
    int half = blockIdx.y;
    int j = threadIdx.x;
    float s = fc1_b[j];
    #pragma unroll
    for (int kc = 0; kc < 10; kc++)
        s += hpart[((size_t)g * 10 + kc) * Hn + j];
    float cntf = fmaxf((float)(gstart[g + 1] - gstart[g]), 1.0f);
    pf[j] = pooled[g * Hn + j] / cntf + s;
    __syncthreads();
    int c = half * 250 + j;
    if (j < 250) {
        float a2 = lin_b[c];
        #pragma unroll 8
        for (int k = 0; k < Hn; k++)
            a2 += pf[k] * lin_w[(size_t)k * Cn + c];
        out[g * Cn + c] = 1.0f / (1.0f + expf(-a2));
    }
}

// ---------------- launch ----------------

extern "C" void kernel_launch(void* const* d_in, const int* in_sizes, int n_in,
                              void* d_out, int out_size, void* d_ws, size_t ws_size,
                              hipStream_t stream) {
    const float* x        = (const float*)d_in[0];
    const int*   eidx     = (const int*)d_in[1];
    const float* eattr    = (const float*)d_in[2];
    const int*   batch    = (const int*)d_in[3];
    const float* seq_emb  = (const float*)d_in[4];
    const float* W1 = (const float*)d_in[5];
    const float* b1 = (const float*)d_in[6];
    const float* g1 = (const float*)d_in[7];
    const float* be1 = (const float*)d_in[8];
    const float* W2 = (const float*)d_in[9];
    const float* b2 = (const float*)d_in[10];
    const float* g2 = (const float*)d_in[11];
    const float* be2 = (const float*)d_in[12];
    const float* W3 = (const float*)d_in[13];
    const float* b3 = (const float*)d_in[14];
    const float* g3 = (const float*)d_in[15];
    const float* be3 = (const float*)d_in[16];
    const float* fc1_w = (const float*)d_in[17];
    const float* fc1_b = (const float*)d_in[18];
    const float* lin_w = (const float*)d_in[19];
    const float* lin_b = (const float*)d_in[20];
    float* out = (float*)d_out;

    const int* row = eidx;
    const int* col = eidx + En;

    char* ws = (char*)d_ws;
    size_t off = 0;
    auto alloc = [&](size_t bytes) -> char* {
        char* p = ws + off;
        off += (bytes + 255) & ~(size_t)255;
        return p;
    };
    ushort* xwb    = (ushort*)alloc((size_t)Nn * Hn * 2);
    ushort* hb     = (ushort*)alloc((size_t)Nn * Hn * 2);
    // ---- zero-init region (contiguous, one memset) ----
    char*  zbase   = ws + off;
    float* deg     = (float*)alloc(Nn * 4);
    int*   counts  = (int*)alloc(Nn * 4);
    float* bvA     = (float*)alloc(Hn * 4);
    float* bvB     = (float*)alloc(Hn * 4);
    float* pooled  = (float*)alloc(Gn * Hn * 4);
    size_t zspan   = (size_t)((ws + off) - zbase);
    // ---- rest ----
    float* dinv    = (float*)alloc(Nn * 4);
    float* dinv2   = (float*)alloc(Nn * 4);
    int*   offsets = (int*)alloc((Nn + 1) * 4);
    int*   cursor  = (int*)alloc(Nn * 4);
    int*   excl    = (int*)alloc(Nn * 4);
    int*   blocksum= (int*)alloc(SNB * 4);
    int*   blockoff= (int*)alloc(SNB * 4);
    int*   csr_row = (int*)alloc(En * 4);
    float* csr_w   = (float*)alloc(En * 4);
    float* scaleA  = (float*)alloc(Hn * 4);
    float* shiftA  = (float*)alloc(Hn * 4);
    int*   gstart  = (int*)alloc((Gn + 1) * 4);
    float* partial = (float*)alloc((size_t)BNB * 512 * 4);
    float* p2      = (float*)alloc(16 * 512 * 4);
    float* hpart   = (float*)alloc((size_t)Gn * 10 * Hn * 4);
    ushort* W1T    = (ushort*)alloc((size_t)Hn * DINn * 2);
    ushort* W2T    = (ushort*)alloc((size_t)Hn * Hn * 2);
    ushort* W3T    = (ushort*)alloc((size_t)Hn * Hn * 2);

    const int TB = 256;
    const int EB = (En + TB - 1) / TB;
    const int NB = (Nn + TB - 1) / TB;

    // ---- prep ----
    hipMemsetAsync(zbase, 0, zspan, stream);
    k_degcnt<<<EB, TB, 0, stream>>>(col, eattr, deg, counts);
    k_dinv<<<NB, TB, 0, stream>>>(deg, dinv, dinv2);
    k_scanA<<<SNB, SCB, 0, stream>>>(counts, excl, blocksum);
    k_scanB<<<1, 128, 0, stream>>>(blocksum, blockoff, offsets);
    k_scanC<<<SNB, SCB, 0, stream>>>(excl, blockoff, offsets, cursor);
    k_fill2<<<EB, TB, 0, stream>>>(row, col, eattr, dinv, cursor, csr_row, csr_w);
    k_gbounds<<<NB, TB, 0, stream>>>(batch, gstart);
    k_wt<<<dim3(DINn / 32, Hn / 32), dim3(32, 8), 0, stream>>>(W1, W1T, DINn);

    // XCD-swizzled 1-D GEMM grid: 313 panels x 4 N-quarters
    const int NBL = (Nn + GBM - 1) / GBM;                 // 313
    const int GGRID = ((NBL + 7) / 8) * 4 * 8;            // 1280
    const int AGB = Nn / 8;

    // ---- layer 1 (f32 A, fused convert) ----
    k_gemm_f32a<<<GGRID, 256, 0, stream>>>(x, W1T, xwb, Nn, DINn, NBL);
    k_agg<<<AGB, 256, 0, stream>>>(xwb, offsets, csr_row, csr_w, dinv2, b1, nullptr, hb, 1);
    k_bnpart<<<BNB, Hn, 0, stream>>>(hb, partial);
    k_bnred<<<16, Hn, 0, stream>>>(partial, p2);
    k_bnfinal2<<<1, Hn, 0, stream>>>(p2, g1, be1, scaleA, shiftA);

    // ---- layer 2 ----
    k_wtb<<<dim3(Hn / 32, Hn / 32), dim3(32, 8), 0, stream>>>(W2, scaleA, shiftA, W2T, bvA);
    k_gemm_bf<<<GGRID, 256, 0, stream>>>(hb, W2T, xwb, Nn, Hn, NBL);
    k_agg<<<AGB, 256, 0, stream>>>(xwb, offsets, csr_row, csr_w, dinv2, b2, bvA, hb, 1);
    k_bnpart<<<BNB, Hn, 0, stream>>>(hb, partial);
    k_bnred<<<16, Hn, 0, stream>>>(partial, p2);
    k_bnfinal2<<<1, Hn, 0, stream>>>(p2, g2, be2, scaleA, shiftA);

    // ---- layer 3 ----
    k_wtb<<<dim3(Hn / 32, Hn / 32), dim3(32, 8), 0, stream>>>(W3, scaleA, shiftA, W3T, bvB);
    k_gemm_bf<<<GGRID, 256, 0, stream>>>(hb, W3T, xwb, Nn, Hn, NBL);
    k_agg<<<AGB, 256, 0, stream>>>(xwb, offsets, csr_row, csr_w, dinv2, b3, bvB, hb, 0);
    k_bnpart<<<BNB, Hn, 0, stream>>>(hb, partial);
    k_bnred<<<16, Hn, 0, stream>>>(partial, p2);
    k_bnfinal2<<<1, Hn, 0, stream>>>(p2, g3, be3, scaleA, shiftA);

    // ---- pooling + head ----
    k_pool2<<<dim3(Gn, PCH), Hn, 0, stream>>>(hb, gstart, scaleA, shiftA, pooled);
    k_head1part<<<dim3(Gn, 10), Hn, 0, stream>>>(seq_emb, fc1_w, hpart);
    k_head2f<<<dim3(Gn, 2), Hn, 0, stream>>>(hpart, fc1_b, pooled, gstart, lin_w, lin_b, out);
}

// Round 18
// 279.207 us; speedup vs baseline: 1.0351x; 1.0351x over previous
//
#include <hip/hip_runtime.h>
#include <hip/hip_bf16.h>
#include <math.h>

#define Nn 20000
#define En 320000
#define Gn 16
#define DINn 1280
#define Hn 256
#define Cn 500
#define EPSn 1e-5f
#define BNB 1024
#define SCB 256
#define SNB ((Nn + SCB - 1) / SCB)   // 79 scan blocks

typedef __attribute__((ext_vector_type(8))) short bf16x8;
typedef __attribute__((ext_vector_type(4))) float f32x4;

__device__ __forceinline__ float b2f(ushort u) {
    return __uint_as_float(((unsigned int)u) << 16);
}
__device__ __forceinline__ ushort f2b(float f) {
    __hip_bfloat16 h = __float2bfloat16(f);
    return *reinterpret_cast<ushort*>(&h);
}

#define GLOAD16(g, l) __builtin_amdgcn_global_load_lds( \
    (const __attribute__((address_space(1))) unsigned int*)(g), \
    (__attribute__((address_space(3))) unsigned int*)(l), 16, 0, 0)

// ---------------- degree+count / CSR build (fused) ----------------

__global__ void k_degcnt(const int* col, const float* ew, float* deg, int* counts) {
    int e = blockIdx.x * blockDim.x + threadIdx.x;
    if (e < En) {
        int c = col[e];
        atomicAdd(&deg[c], ew[e]);
        atomicAdd(&counts[c], 1);
    }
}

__global__ void k_dinv(const float* deg, float* dinv, float* dinv2) {
    int i = blockIdx.x * blockDim.x + threadIdx.x;
    if (i < Nn) {
        float d = deg[i] + 1.0f;
        float r = rsqrtf(d);
        dinv[i] = r;
        dinv2[i] = 1.0f / d;
    }
}

// ---------------- multi-block exclusive scan ----------------

__global__ __launch_bounds__(SCB) void k_scanA(const int* __restrict__ counts,
                                               int* __restrict__ excl,
                                               int* __restrict__ blocksum) {
    __shared__ int sd[SCB];
    int t = threadIdx.x, b = blockIdx.x;
    int i = b * SCB + t;
    int v = (i < Nn) ? counts[i] : 0;
    sd[t] = v;
    __syncthreads();
    #pragma unroll
    for (int o = 1; o < SCB; o <<= 1) {
        int tv = (t >= o) ? sd[t - o] : 0;
        __syncthreads();
        sd[t] += tv;
        __syncthreads();
    }
    if (i < Nn) excl[i] = sd[t] - v;
    if (t == SCB - 1) blocksum[b] = sd[t];
}

__global__ __launch_bounds__(128) void k_scanB(const int* __restrict__ blocksum,
                                               int* __restrict__ blockoff,
                                               int* __restrict__ offsets) {
    __shared__ int sd[128];
    int t = threadIdx.x;
    int v = (t < SNB) ? blocksum[t] : 0;
    sd[t] = v;
    __syncthreads();
    #pragma unroll
    for (int o = 1; o < 128; o <<= 1) {
        int tv = (t >= o) ? sd[t - o] : 0;
        __syncthreads();
        sd[t] += tv;
        __syncthreads();
    }
    if (t < SNB) blockoff[t] = sd[t] - v;
    if (t == SNB - 1) offsets[Nn] = sd[t];
}

__global__ __launch_bounds__(SCB) void k_scanC(const int* __restrict__ excl,
                                               const int* __restrict__ blockoff,
                                               int* __restrict__ offsets,
                                               int* __restrict__ cursor) {
    int b = blockIdx.x;
    int i = b * SCB + threadIdx.x;
    if (i < Nn) {
        int o = excl[i] + blockoff[b];
        offsets[i] = o;
        cursor[i] = o;
    }
}

// fill with fused norm computation: csr_w = dinv[r]*ew*dinv[c]
__global__ void k_fill2(const int* row, const int* col, const float* ew,
                        const float* dinv, int* cursor,
                        int* csr_row, float* csr_w) {
    int e = blockIdx.x * blockDim.x + threadIdx.x;
    if (e < En) {
        int r = row[e], c = col[e];
        int p = atomicAdd(&cursor[c], 1);
        csr_row[p] = r;
        csr_w[p] = dinv[r] * ew[e] * dinv[c];
    }
}

// ---------------- group bounds from sorted batch ----------------

__global__ void k_gbounds(const int* __restrict__ batch, int* __restrict__ gstart) {
    int i = blockIdx.x * blockDim.x + threadIdx.x;
    if (i >= Nn) return;
    int b = batch[i];
    if (i == 0) {
        for (int g = 0; g <= b; g++) gstart[g] = 0;
    } else {
        int pb = batch[i - 1];
        for (int g = pb + 1; g <= b; g++) gstart[g] = i;
    }
    if (i == Nn - 1) {
        for (int g = b + 1; g <= Gn; g++) gstart[g] = Nn;
    }
}

// ---------------- plain weight transpose (W1) ----------------

__global__ __launch_bounds__(256) void k_wt(const float* __restrict__ W,
                                            ushort* __restrict__ WT, int K) {
    __shared__ float tile[32][33];
    int k0 = blockIdx.x * 32, n0 = blockIdx.y * 32;
    int tx = threadIdx.x, ty = threadIdx.y;   // (32, 8)
    #pragma unroll
    for (int i = 0; i < 32; i += 8)
        tile[ty + i][tx] = W[(size_t)(k0 + ty + i) * Hn + n0 + tx];
    __syncthreads();
    #pragma unroll
    for (int i = 0; i < 32; i += 8)
        WT[(size_t)(n0 + ty + i) * K + k0 + tx] = f2b(tile[tx][ty + i]);
}

// ---------------- affine-folded weight transform (W2/W3) ----------------

__global__ __launch_bounds__(256) void k_wtb(const float* __restrict__ W,
                                             const float* __restrict__ scaleA,
                                             const float* __restrict__ shiftA,
                                             ushort* __restrict__ WT,
                                             float* __restrict__ bv) {
    __shared__ float tile[32][33];
    int k0 = blockIdx.x * 32, n0 = blockIdx.y * 32;
    int tx = threadIdx.x, ty = threadIdx.y;   // (32, 8)
    #pragma unroll
    for (int i = 0; i < 32; i += 8)
        tile[ty + i][tx] = W[(size_t)(k0 + ty + i) * Hn + n0 + tx];
    __syncthreads();
    float sc = scaleA[k0 + tx], sh = shiftA[k0 + tx];
    #pragma unroll
    for (int i = 0; i < 32; i += 8) {
        float w = tile[tx][ty + i];   // k = k0+tx, n = n0+ty+i
        WT[(size_t)(n0 + ty + i) * Hn + k0 + tx] = f2b(w * sc);
        float pb = w * sh;
        #pragma unroll
        for (int o = 16; o > 0; o >>= 1) pb += __shfl_down(pb, o, 32);
        if (tx == 0) atomicAdd(&bv[n0 + ty + i], pb);
    }
}

// ---------------- GEMM layer 1: f32 A staged via regs (fused bf16 convert) ----------------

#define GBM 64
#define GBN 128
#define GBK 64

__global__ __launch_bounds__(256) void k_gemm_f32a(
    const float* __restrict__ A, const ushort* __restrict__ BT,
    ushort* __restrict__ C, int M, int K, int NBL)
{
    __shared__ ushort Asl[2][GBM][GBK];   // 16 KB
    __shared__ ushort Bsl[2][GBN][GBK];   // 32 KB
    const int id = blockIdx.x;
    const int k8 = id >> 3;
    const int r8 = id & 7;
    const int p = (k8 >> 1) * 8 + r8;
    const int bnk = k8 & 1;
    if (p >= NBL) return;
    const int bm = p * GBM;
    const int bn = bnk * GBN;
    const int tid = threadIdx.x;
    const int lane = tid & 63;
    const int wid = tid >> 6;
    const int wm = wid >> 1, wn = wid & 1;
    const int l15 = lane & 15, l16 = lane >> 4;

    const int lrow = lane >> 3;
    const int lcolb = 16 * ((lane & 7) ^ lrow);
    const int arow = tid >> 2;
    const int acol = (tid & 3) * 16;
    int agrow = bm + arow; if (agrow >= M) agrow = M - 1;
    const int awoff0 = (acol * 2) ^ ((arow & 7) << 4);
    const int awoff1 = (acol * 2 + 16) ^ ((arow & 7) << 4);

    f32x4 acc[2][4] = {};
    const int nt = K / GBK;

    float4 fa0, fa1, fa2, fa3;
    auto LOADA = [&](int t) {
        const float4* ap = reinterpret_cast<const float4*>(
            &A[(size_t)agrow * K + t * GBK + acol]);
        fa0 = ap[0]; fa1 = ap[1]; fa2 = ap[2]; fa3 = ap[3];
    };
    auto WRITEA = [&](int buf) {
        ushort t16[16];
        t16[0]  = f2b(fa0.x); t16[1]  = f2b(fa0.y); t16[2]  = f2b(fa0.z); t16[3]  = f2b(fa0.w);
        t16[4]  = f2b(fa1.x); t16[5]  = f2b(fa1.y); t16[6]  = f2b(fa1.z); t16[7]  = f2b(fa1.w);
        t16[8]  = f2b(fa2.x); t16[9]  = f2b(fa2.y); t16[10] = f2b(fa2.z); t16[11] = f2b(fa2.w);
        t16[12] = f2b(fa3.x); t16[13] = f2b(fa3.y); t16[14] = f2b(fa3.z); t16[15] = f2b(fa3.w);
        char* base = (char*)&Asl[buf][arow][0];
        *reinterpret_cast<uint4*>(base + awoff0) = *reinterpret_cast<uint4*>(&t16[0]);
        *reinterpret_cast<uint4*>(base + awoff1) = *reinterpret_cast<uint4*>(&t16[8]);
    };
    auto STAGEB = [&](int buf, int t) {
        const int k0 = t * GBK;
        #pragma unroll
        for (int c = 0; c < 4; c++) {
            int chunk = wid * 4 + c;
            int grow = bn + chunk * 8 + lrow;
            const char* src = (const char*)&BT[(size_t)grow * K + k0] + lcolb;
            GLOAD16(src, &Bsl[buf][chunk * 8][0]);
        }
    };

    LOADA(0);
    STAGEB(0, 0);
    WRITEA(0);
    __syncthreads();

    for (int t = 0; t < nt; t++) {
        const int cur = t & 1;
        if (t + 1 < nt) { LOADA(t + 1); STAGEB(cur ^ 1, t + 1); }
        #pragma unroll
        for (int ks = 0; ks < 2; ks++) {
            bf16x8 afr[2], bfr[4];
            #pragma unroll
            for (int i = 0; i < 2; i++) {
                int r = wm * 32 + i * 16 + l15;
                int cb = (ks * 64 + l16 * 16) ^ ((r & 7) << 4);
                afr[i] = *reinterpret_cast<const bf16x8*>((const char*)&Asl[cur][r][0] + cb);
            }
            #pragma unroll
            for (int j = 0; j < 4; j++) {
                int r = wn * 64 + j * 16 + l15;
                int cb = (ks * 64 + l16 * 16) ^ ((r & 7) << 4);
                bfr[j] = *reinterpret_cast<const bf16x8*>((const char*)&Bsl[cur][r][0] + cb);
            }
            #pragma unroll
            for (int i = 0; i < 2; i++)
                #pragma unroll
                for (int j = 0; j < 4; j++)
                    acc[i][j] = __builtin_amdgcn_mfma_f32_16x16x32_bf16(afr[i], bfr[j], acc[i][j], 0, 0, 0);
        }
        if (t + 1 < nt) WRITEA(cur ^ 1);
        __syncthreads();
    }

    #pragma unroll
    for (int i = 0; i < 2; i++) {
        #pragma unroll
        for (int r = 0; r < 4; r++) {
            int grow = bm + wm * 32 + i * 16 + l16 * 4 + r;
            if (grow < M) {
                #pragma unroll
                for (int j = 0; j < 4; j++)
                    C[(size_t)grow * Hn + bn + wn * 64 + j * 16 + l15] = f2b(acc[i][j][r]);
            }
        }
    }
}

// ---------------- bf16 GEMM (layers 2/3): 2-phase double-buffered prefetch ----------------

__global__ __launch_bounds__(256) void k_gemm_bf(
    const ushort* __restrict__ A, const ushort* __restrict__ BT,
    ushort* __restrict__ C, int M, int K, int NBL)
{
    __shared__ ushort Asl[2][GBM][GBK];
    __shared__ ushort Bsl[2][GBN][GBK];
    const int id = blockIdx.x;
    const int k8 = id >> 3;
    const int r8 = id & 7;
    const int p = (k8 >> 1) * 8 + r8;
    const int bnk = k8 & 1;
    if (p >= NBL) return;
    const int bm = p * GBM;
    const int bn = bnk * GBN;
    const int tid = threadIdx.x;
    const int lane = tid & 63;
    const int wid = tid >> 6;
    const int wm = wid >> 1, wn = wid & 1;
    const int l15 = lane & 15, l16 = lane >> 4;

    const int lrow = lane >> 3;
    const int lcolb = 16 * ((lane & 7) ^ lrow);

    f32x4 acc[2][4] = {};
    const int nt = K / GBK;

    auto STAGE = [&](int buf, int t) {
        const int k0 = t * GBK;
        #pragma unroll
        for (int c = 0; c < 2; c++) {
            int chunk = wid * 2 + c;
            int grow = bm + chunk * 8 + lrow;
            if (grow >= M) grow = M - 1;
            const char* src = (const char*)&A[(size_t)grow * K + k0] + lcolb;
            GLOAD16(src, &Asl[buf][chunk * 8][0]);
        }
        #pragma unroll
        for (int c = 0; c < 4; c++) {
            int chunk = wid * 4 + c;
            int grow = bn + chunk * 8 + lrow;
            const char* src = (const char*)&BT[(size_t)grow * K + k0] + lcolb;
            GLOAD16(src, &Bsl[buf][chunk * 8][0]);
        }
    };

    STAGE(0, 0);
    __syncthreads();

    for (int t = 0; t < nt; t++) {
        const int cur = t & 1;
        if (t + 1 < nt) STAGE(cur ^ 1, t + 1);
        #pragma unroll
        for (int ks = 0; ks < 2; ks++) {
            bf16x8 afr[2], bfr[4];
            #pragma unroll
            for (int i = 0; i < 2; i++) {
                int r = wm * 32 + i * 16 + l15;
                int cb = (ks * 64 + l16 * 16) ^ ((r & 7) << 4);
                afr[i] = *reinterpret_cast<const bf16x8*>((const char*)&Asl[cur][r][0] + cb);
            }
            #pragma unroll
            for (int j = 0; j < 4; j++) {
                int r = wn * 64 + j * 16 + l15;
                int cb = (ks * 64 + l16 * 16) ^ ((r & 7) << 4);
                bfr[j] = *reinterpret_cast<const bf16x8*>((const char*)&Bsl[cur][r][0] + cb);
            }
            #pragma unroll
            for (int i = 0; i < 2; i++)
                #pragma unroll
                for (int j = 0; j < 4; j++)
                    acc[i][j] = __builtin_amdgcn_mfma_f32_16x16x32_bf16(afr[i], bfr[j], acc[i][j], 0, 0, 0);
        }
        __syncthreads();
    }

    #pragma unroll
    for (int i = 0; i < 2; i++) {
        #pragma unroll
        for (int r = 0; r < 4; r++) {
            int grow = bm + wm * 32 + i * 16 + l16 * 4 + r;
            if (grow < M) {
                #pragma unroll
                for (int j = 0; j < 4; j++)
                    C[(size_t)grow * Hn + bn + wn * 64 + j * 16 + l15] = f2b(acc[i][j][r]);
            }
        }
    }
}

// ---------------- aggregation: half-wave per node, 4-deep ILP gather ----------------

__device__ __forceinline__ void agg_accum(float* acc, float w, const uint4& v) {
    unsigned int u;
    u = v.x; acc[0] += w * b2f((ushort)u); acc[1] += w * b2f((ushort)(u >> 16));
    u = v.y; acc[2] += w * b2f((ushort)u); acc[3] += w * b2f((ushort)(u >> 16));
    u = v.z; acc[4] += w * b2f((ushort)u); acc[5] += w * b2f((ushort)(u >> 16));
    u = v.w; acc[6] += w * b2f((ushort)u); acc[7] += w * b2f((ushort)(u >> 16));
}

__global__ __launch_bounds__(256) void k_agg(const ushort* __restrict__ xw,
                                             const int* __restrict__ offsets,
                                             const int* __restrict__ csr_row,
                                             const float* __restrict__ csr_w,
                                             const float* __restrict__ dinv2,
                                             const float* __restrict__ bias,
                                             const float* __restrict__ bv,
                                             ushort* __restrict__ outp, int do_relu) {
    int node = blockIdx.x * 8 + (threadIdx.x >> 5);
    int l32 = threadIdx.x & 31;
    int s = offsets[node], e = offsets[node + 1];
    const uint4* xw4 = reinterpret_cast<const uint4*>(xw);

    float acc[8] = {};
    float wsum = 0.f;
    int k = s;
    for (; k + 4 <= e; k += 4) {
        int r0 = csr_row[k],     r1 = csr_row[k + 1];
        int r2 = csr_row[k + 2], r3 = csr_row[k + 3];
        float w0 = csr_w[k],     w1 = csr_w[k + 1];
        float w2 = csr_w[k + 2], w3 = csr_w[k + 3];
        uint4 v0 = xw4[(size_t)r0 * 32 + l32];
        uint4 v1 = xw4[(size_t)r1 * 32 + l32];
        uint4 v2 = xw4[(size_t)r2 * 32 + l32];
        uint4 v3 = xw4[(size_t)r3 * 32 + l32];
        wsum += (w0 + w1) + (w2 + w3);
        agg_accum(acc, w0, v0);
        agg_accum(acc, w1, v1);
        agg_accum(acc, w2, v2);
        agg_accum(acc, w3, v3);
    }
    for (; k < e; k++) {
        int r = csr_row[k];
        float w = csr_w[k];
        uint4 v = xw4[(size_t)r * 32 + l32];
        wsum += w;
        agg_accum(acc, w, v);
    }
    float d2 = dinv2[node];
    wsum += d2;
    uint4 vs = xw4[(size_t)node * 32 + l32];
    agg_accum(acc, d2, vs);

    const float4* bp = reinterpret_cast<const float4*>(&bias[l32 * 8]);
    float4 bb0 = bp[0], bb1 = bp[1];
    acc[0] += bb0.x; acc[1] += bb0.y; acc[2] += bb0.z; acc[3] += bb0.w;
    acc[4] += bb1.x; acc[5] += bb1.y; acc[6] += bb1.z; acc[7] += bb1.w;
    if (bv) {
        const float4* vp = reinterpret_cast<const float4*>(&bv[l32 * 8]);
        float4 bv0 = vp[0], bv1 = vp[1];
        acc[0] += wsum * bv0.x; acc[1] += wsum * bv0.y;
        acc[2] += wsum * bv0.z; acc[3] += wsum * bv0.w;
        acc[4] += wsum * bv1.x; acc[5] += wsum * bv1.y;
        acc[6] += wsum * bv1.z; acc[7] += wsum * bv1.w;
    }
    if (do_relu) {
        #pragma unroll
        for (int q = 0; q < 8; q++) acc[q] = fmaxf(acc[q], 0.f);
    }
    uint4 o;
    o.x = (unsigned int)f2b(acc[0]) | ((unsigned int)f2b(acc[1]) << 16);
    o.y = (unsigned int)f2b(acc[2]) | ((unsigned int)f2b(acc[3]) << 16);
    o.z = (unsigned int)f2b(acc[4]) | ((unsigned int)f2b(acc[5]) << 16);
    o.w = (unsigned int)f2b(acc[6]) | ((unsigned int)f2b(acc[7]) << 16);
    reinterpret_cast<uint4*>(outp)[(size_t)node * 32 + l32] = o;
}

// ---------------- batch-norm stats ----------------

__global__ __launch_bounds__(256) void k_bnpart(const ushort* __restrict__ h,
                                                float* __restrict__ partial) {
    int f = threadIdx.x;
    int blk = blockIdx.x;
    float s = 0.0f, ss = 0.0f;
    for (int i = blk; i < Nn; i += BNB) {
        float v = b2f(h[(size_t)i * Hn + f]);
        s += v;
        ss += v * v;
    }
    partial[(size_t)blk * 512 + f] = s;
    partial[(size_t)blk * 512 + 256 + f] = ss;
}

__global__ __launch_bounds__(256) void k_bnred(const float* __restrict__ partial,
                                               float* __restrict__ p2) {
    int f = threadIdx.x;
    int b = blockIdx.x;
    int b0 = b * 64;
    float s = 0.0f, ss = 0.0f;
    for (int j = 0; j < 64; j++) {
        const float* p = &partial[(size_t)(b0 + j) * 512];
        s += p[f];
        ss += p[256 + f];
    }
    p2[b * 512 + f] = s;
    p2[b * 512 + 256 + f] = ss;
}

__global__ void k_bnfinal2(const float* __restrict__ p2, const float* g, const float* be,
                           float* scaleA, float* shiftA) {
    int f = threadIdx.x;
    float s = 0.f, ss = 0.f;
    #pragma unroll
    for (int j = 0; j < 16; j++) {
        s += p2[j * 512 + f];
        ss += p2[j * 512 + 256 + f];
    }
    float mean = s / (float)Nn;
    float var = ss / (float)Nn - mean * mean;
    float a = g[f] * rsqrtf(var + EPSn);
    scaleA[f] = a;
    shiftA[f] = be[f] - mean * a;
}

// ---------------- pooling ----------------

#define PCH 32

__global__ __launch_bounds__(256) void k_pool2(const ushort* __restrict__ h,
                                               const int* __restrict__ gstart,
                                               const float* __restrict__ scaleA,
                                               const float* __restrict__ shiftA,
                                               float* __restrict__ pooled) {
    int g = blockIdx.x;
    int chunk = blockIdx.y;
    int f = threadIdx.x;
    int s = gstart[g], e = gstart[g + 1];
    int len = e - s;
    if (len <= 0) return;
    int per = (len + PCH - 1) / PCH;
    int cs = s + chunk * per;
    int ce = cs + per; if (ce > e) ce = e;
    if (cs >= ce) return;
    float sc = scaleA[f], sh = shiftA[f];
    float acc = 0.0f;
    for (int i = cs; i < ce; i++)
        acc += b2f(h[(size_t)i * Hn + f]) * sc + sh;
    atomicAdd(&pooled[g * Hn + f], acc);
}

// ---------------- head: fc1 partials (no atomics) + finish ----------------

__global__ __launch_bounds__(256) void k_head1part(const float* __restrict__ seq_emb,
                                                   const float* __restrict__ fc1_w,
                                                   float* __restrict__ hpart) {
    int g = blockIdx.x;
    int kc = blockIdx.y;
    int j = threadIdx.x;
    const float* se = &seq_emb[(size_t)g * DINn + kc * 128];
    const float* w = &fc1_w[(size_t)kc * 128 * Hn + j];
    float acc = 0.0f;
    #pragma unroll 8
    for (int k = 0; k < 128; k++)
        acc += se[k] * w[(size_t)k * Hn];
    hpart[((size_t)g * 10 + kc) * Hn + j] = acc;
}

__global__ __launch_bounds__(256) void k_head2f(const float* __restrict__ hpart,
                                                const float* __restrict__ fc1_b,
                                                const float* __restrict__ pooled,
                                                const int* __restrict__ gstart,
                                                const float* __restrict__ lin_w,
                                                const float* __restrict__ lin_b,
                                                float* __restrict__ out) {
    __shared__ float pf[Hn];
    int g = blockIdx.x;
    int half = blockIdx.y;
    int j = threadIdx.x;
    float s = fc1_b[j];
    #pragma unroll
    for (int kc = 0; kc < 10; kc++)
        s += hpart[((size_t)g * 10 + kc) * Hn + j];
    float cntf = fmaxf((float)(gstart[g + 1] - gstart[g]), 1.0f);
    pf[j] = pooled[g * Hn + j] / cntf + s;
    __syncthreads();
    int c = half * 250 + j;
    if (j < 250) {
        float a2 = lin_b[c];
        #pragma unroll 8
        for (int k = 0; k < Hn; k++)
            a2 += pf[k] * lin_w[(size_t)k * Cn + c];
        out[g * Cn + c] = 1.0f / (1.0f + expf(-a2));
    }
}

// ---------------- launch ----------------

extern "C" void kernel_launch(void* const* d_in, const int* in_sizes, int n_in,
                              void* d_out, int out_size, void* d_ws, size_t ws_size,
                              hipStream_t stream) {
    const float* x        = (const float*)d_in[0];
    const int*   eidx     = (const int*)d_in[1];
    const float* eattr    = (const float*)d_in[2];
    const int*   batch    = (const int*)d_in[3];
    const float* seq_emb  = (const float*)d_in[4];
    const float* W1 = (const float*)d_in[5];
    const float* b1 = (const float*)d_in[6];
    const float* g1 = (const float*)d_in[7];
    const float* be1 = (const float*)d_in[8];
    const float* W2 = (const float*)d_in[9];
    const float* b2 = (const float*)d_in[10];
    const float* g2 = (const float*)d_in[11];
    const float* be2 = (const float*)d_in[12];
    const float* W3 = (const float*)d_in[13];
    const float* b3 = (const float*)d_in[14];
    const float* g3 = (const float*)d_in[15];
    const float* be3 = (const float*)d_in[16];
    const float* fc1_w = (const float*)d_in[17];
    const float* fc1_b = (const float*)d_in[18];
    const float* lin_w = (const float*)d_in[19];
    const float* lin_b = (const float*)d_in[20];
    float* out = (float*)d_out;

    const int* row = eidx;
    const int* col = eidx + En;

    char* ws = (char*)d_ws;
    size_t off = 0;
    auto alloc = [&](size_t bytes) -> char* {
        char* p = ws + off;
        off += (bytes + 255) & ~(size_t)255;
        return p;
    };
    ushort* xwb    = (ushort*)alloc((size_t)Nn * Hn * 2);
    ushort* hb     = (ushort*)alloc((size_t)Nn * Hn * 2);
    // ---- zero-init region (contiguous, one memset) ----
    char*  zbase   = ws + off;
    float* deg     = (float*)alloc(Nn * 4);
    int*   counts  = (int*)alloc(Nn * 4);
    float* bvA     = (float*)alloc(Hn * 4);
    float* bvB     = (float*)alloc(Hn * 4);
    float* pooled  = (float*)alloc(Gn * Hn * 4);
    size_t zspan   = (size_t)((ws + off) - zbase);
    // ---- rest ----
    float* dinv    = (float*)alloc(Nn * 4);
    float* dinv2   = (float*)alloc(Nn * 4);
    int*   offsets = (int*)alloc((Nn + 1) * 4);
    int*   cursor  = (int*)alloc(Nn * 4);
    int*   excl    = (int*)alloc(Nn * 4);
    int*   blocksum= (int*)alloc(SNB * 4);
    int*   blockoff= (int*)alloc(SNB * 4);
    int*   csr_row = (int*)alloc(En * 4);
    float* csr_w   = (float*)alloc(En * 4);
    float* scaleA  = (float*)alloc(Hn * 4);
    float* shiftA  = (float*)alloc(Hn * 4);
    int*   gstart  = (int*)alloc((Gn + 1) * 4);
    float* partial = (float*)alloc((size_t)BNB * 512 * 4);
    float* p2      = (float*)alloc(16 * 512 * 4);
    float* hpart   = (float*)alloc((size_t)Gn * 10 * Hn * 4);
    ushort* W1T    = (ushort*)alloc((size_t)Hn * DINn * 2);
    ushort* W2T    = (ushort*)alloc((size_t)Hn * Hn * 2);
    ushort* W3T    = (ushort*)alloc((size_t)Hn * Hn * 2);

    const int TB = 256;
    const int EB = (En + TB - 1) / TB;
    const int NB = (Nn + TB - 1) / TB;

    // ---- prep ----
    hipMemsetAsync(zbase, 0, zspan, stream);
    k_degcnt<<<EB, TB, 0, stream>>>(col, eattr, deg, counts);
    k_dinv<<<NB, TB, 0, stream>>>(deg, dinv, dinv2);
    k_scanA<<<SNB, SCB, 0, stream>>>(counts, excl, blocksum);
    k_scanB<<<1, 128, 0, stream>>>(blocksum, blockoff, offsets);
    k_scanC<<<SNB, SCB, 0, stream>>>(excl, blockoff, offsets, cursor);
    k_fill2<<<EB, TB, 0, stream>>>(row, col, eattr, dinv, cursor, csr_row, csr_w);
    k_gbounds<<<NB, TB, 0, stream>>>(batch, gstart);
    k_wt<<<dim3(DINn / 32, Hn / 32), dim3(32, 8), 0, stream>>>(W1, W1T, DINn);

    // XCD-pair-swizzled 1-D GEMM grid
    const int NBL = (Nn + GBM - 1) / GBM;           // 313
    const int GGRID = ((NBL * 2 + 15) / 16) * 16;   // 640
    const int AGB = Nn / 8;

    // ---- layer 1 (f32 A, fused convert) ----
    k_gemm_f32a<<<GGRID, 256, 0, stream>>>(x, W1T, xwb, Nn, DINn, NBL);
    k_agg<<<AGB, 256, 0, stream>>>(xwb, offsets, csr_row, csr_w, dinv2, b1, nullptr, hb, 1);
    k_bnpart<<<BNB, Hn, 0, stream>>>(hb, partial);
    k_bnred<<<16, Hn, 0, stream>>>(partial, p2);
    k_bnfinal2<<<1, Hn, 0, stream>>>(p2, g1, be1, scaleA, shiftA);

    // ---- layer 2 ----
    k_wtb<<<dim3(Hn / 32, Hn / 32), dim3(32, 8), 0, stream>>>(W2, scaleA, shiftA, W2T, bvA);
    k_gemm_bf<<<GGRID, 256, 0, stream>>>(hb, W2T, xwb, Nn, Hn, NBL);
    k_agg<<<AGB, 256, 0, stream>>>(xwb, offsets, csr_row, csr_w, dinv2, b2, bvA, hb, 1);
    k_bnpart<<<BNB, Hn, 0, stream>>>(hb, partial);
    k_bnred<<<16, Hn, 0, stream>>>(partial, p2);
    k_bnfinal2<<<1, Hn, 0, stream>>>(p2, g2, be2, scaleA, shiftA);

    // ---- layer 3 ----
    k_wtb<<<dim3(Hn / 32, Hn / 32), dim3(32, 8), 0, stream>>>(W3, scaleA, shiftA, W3T, bvB);
    k_gemm_bf<<<GGRID, 256, 0, stream>>>(hb, W3T, xwb, Nn, Hn, NBL);
    k_agg<<<AGB, 256, 0, stream>>>(xwb, offsets, csr_row, csr_w, dinv2, b3, bvB, hb, 0);
    k_bnpart<<<BNB, Hn, 0, stream>>>(hb, partial);
    k_bnred<<<16, Hn, 0, stream>>>(partial, p2);
    k_bnfinal2<<<1, Hn, 0, stream>>>(p2, g3, be3, scaleA, shiftA);

    // ---- pooling + head ----
    k_pool2<<<dim3(Gn, PCH), Hn, 0, stream>>>(hb, gstart, scaleA, shiftA, pooled);
    k_head1part<<<dim3(Gn, 10), Hn, 0, stream>>>(seq_emb, fc1_w, hpart);
    k_head2f<<<dim3(Gn, 2), Hn, 0, stream>>>(hpart, fc1_b, pooled, gstart, lin_w, lin_b, out);
}

// Round 19
// 271.896 us; speedup vs baseline: 1.0629x; 1.0269x over previous
//
#include <hip/hip_runtime.h>
#include <hip/hip_bf16.h>
#include <math.h>

#define Nn 20000
#define En 320000
#define Gn 16
#define DINn 1280
#define Hn 256
#define Cn 500
#define EPSn 1e-5f
#define BNB 1024
#define SCB 256
#define SNB ((Nn + SCB - 1) / SCB)   // 79 scan blocks

typedef __attribute__((ext_vector_type(8))) short bf16x8;
typedef __attribute__((ext_vector_type(4))) float f32x4;

__device__ __forceinline__ float b2f(ushort u) {
    return __uint_as_float(((unsigned int)u) << 16);
}
__device__ __forceinline__ ushort f2b(float f) {
    __hip_bfloat16 h = __float2bfloat16(f);
    return *reinterpret_cast<ushort*>(&h);
}

#define GLOAD16(g, l) __builtin_amdgcn_global_load_lds( \
    (const __attribute__((address_space(1))) unsigned int*)(g), \
    (__attribute__((address_space(3))) unsigned int*)(l), 16, 0, 0)

// reduce 16 p2 rows -> BN scale/shift for feature f
__device__ __forceinline__ void bn_from_p2(const float* __restrict__ p2,
                                           const float* __restrict__ g,
                                           const float* __restrict__ be,
                                           int f, float& sc, float& sh) {
    float s = 0.f, ss = 0.f;
    #pragma unroll
    for (int j = 0; j < 16; j++) {
        s += p2[j * 512 + f];
        ss += p2[j * 512 + 256 + f];
    }
    float mean = s / (float)Nn;
    float var = ss / (float)Nn - mean * mean;
    float a = g[f] * rsqrtf(var + EPSn);
    sc = a;
    sh = be[f] - mean * a;
}

// ---------------- degree+count (fused) ----------------

__global__ void k_degcnt(const int* col, const float* ew, float* deg, int* counts) {
    int e = blockIdx.x * blockDim.x + threadIdx.x;
    if (e < En) {
        int c = col[e];
        atomicAdd(&deg[c], ew[e]);
        atomicAdd(&counts[c], 1);
    }
}

// ---------------- multi-block exclusive scan (A fused with dinv) ----------------

__global__ __launch_bounds__(SCB) void k_scanA(const int* __restrict__ counts,
                                               const float* __restrict__ deg,
                                               int* __restrict__ excl,
                                               int* __restrict__ blocksum,
                                               float* __restrict__ dinv,
                                               float* __restrict__ dinv2) {
    __shared__ int sd[SCB];
    int t = threadIdx.x, b = blockIdx.x;
    int i = b * SCB + t;
    int v = (i < Nn) ? counts[i] : 0;
    sd[t] = v;
    __syncthreads();
    #pragma unroll
    for (int o = 1; o < SCB; o <<= 1) {
        int tv = (t >= o) ? sd[t - o] : 0;
        __syncthreads();
        sd[t] += tv;
        __syncthreads();
    }
    if (i < Nn) {
        excl[i] = sd[t] - v;
        float d = deg[i] + 1.0f;
        dinv[i] = rsqrtf(d);
        dinv2[i] = 1.0f / d;
    }
    if (t == SCB - 1) blocksum[b] = sd[t];
}

__global__ __launch_bounds__(128) void k_scanB(const int* __restrict__ blocksum,
                                               int* __restrict__ blockoff,
                                               int* __restrict__ offsets) {
    __shared__ int sd[128];
    int t = threadIdx.x;
    int v = (t < SNB) ? blocksum[t] : 0;
    sd[t] = v;
    __syncthreads();
    #pragma unroll
    for (int o = 1; o < 128; o <<= 1) {
        int tv = (t >= o) ? sd[t - o] : 0;
        __syncthreads();
        sd[t] += tv;
        __syncthreads();
    }
    if (t < SNB) blockoff[t] = sd[t] - v;
    if (t == SNB - 1) offsets[Nn] = sd[t];
}

// scanC fused with gbounds (same i<Nn domain)
__global__ __launch_bounds__(SCB) void k_scanC(const int* __restrict__ excl,
                                               const int* __restrict__ blockoff,
                                               const int* __restrict__ batch,
                                               int* __restrict__ offsets,
                                               int* __restrict__ cursor,
                                               int* __restrict__ gstart) {
    int b = blockIdx.x;
    int i = b * SCB + threadIdx.x;
    if (i >= Nn) return;
    int o = excl[i] + blockoff[b];
    offsets[i] = o;
    cursor[i] = o;
    int bt = batch[i];
    if (i == 0) {
        for (int g = 0; g <= bt; g++) gstart[g] = 0;
    } else {
        int pb = batch[i - 1];
        for (int g = pb + 1; g <= bt; g++) gstart[g] = i;
    }
    if (i == Nn - 1) {
        for (int g = bt + 1; g <= Gn; g++) gstart[g] = Nn;
    }
}

// fill with fused norm computation: csr_w = dinv[r]*ew*dinv[c]
__global__ void k_fill2(const int* row, const int* col, const float* ew,
                        const float* dinv, int* cursor,
                        int* csr_row, float* csr_w) {
    int e = blockIdx.x * blockDim.x + threadIdx.x;
    if (e < En) {
        int r = row[e], c = col[e];
        int p = atomicAdd(&cursor[c], 1);
        csr_row[p] = r;
        csr_w[p] = dinv[r] * ew[e] * dinv[c];
    }
}

// ---------------- plain weight transpose (W1) ----------------

__global__ __launch_bounds__(256) void k_wt(const float* __restrict__ W,
                                            ushort* __restrict__ WT, int K) {
    __shared__ float tile[32][33];
    int k0 = blockIdx.x * 32, n0 = blockIdx.y * 32;
    int tx = threadIdx.x, ty = threadIdx.y;   // (32, 8)
    #pragma unroll
    for (int i = 0; i < 32; i += 8)
        tile[ty + i][tx] = W[(size_t)(k0 + ty + i) * Hn + n0 + tx];
    __syncthreads();
    #pragma unroll
    for (int i = 0; i < 32; i += 8)
        WT[(size_t)(n0 + ty + i) * K + k0 + tx] = f2b(tile[tx][ty + i]);
}

// ---------------- affine-folded weight transform (W2/W3), BN-final fused ----------------

__global__ __launch_bounds__(256) void k_wtb(const float* __restrict__ W,
                                             const float* __restrict__ p2,
                                             const float* __restrict__ g,
                                             const float* __restrict__ be,
                                             ushort* __restrict__ WT,
                                             float* __restrict__ bv) {
    __shared__ float tile[32][33];
    int k0 = blockIdx.x * 32, n0 = blockIdx.y * 32;
    int tx = threadIdx.x, ty = threadIdx.y;   // (32, 8)
    #pragma unroll
    for (int i = 0; i < 32; i += 8)
        tile[ty + i][tx] = W[(size_t)(k0 + ty + i) * Hn + n0 + tx];
    __syncthreads();
    float sc, sh;
    bn_from_p2(p2, g, be, k0 + tx, sc, sh);
    #pragma unroll
    for (int i = 0; i < 32; i += 8) {
        float w = tile[tx][ty + i];   // k = k0+tx, n = n0+ty+i
        WT[(size_t)(n0 + ty + i) * Hn + k0 + tx] = f2b(w * sc);
        float pb = w * sh;
        #pragma unroll
        for (int o = 16; o > 0; o >>= 1) pb += __shfl_down(pb, o, 32);
        if (tx == 0) atomicAdd(&bv[n0 + ty + i], pb);
    }
}

// ---------------- GEMM layer 1: f32 A staged via regs (fused bf16 convert) ----------------

#define GBM 64
#define GBN 128
#define GBK 64

__global__ __launch_bounds__(256) void k_gemm_f32a(
    const float* __restrict__ A, const ushort* __restrict__ BT,
    ushort* __restrict__ C, int M, int K, int NBL)
{
    __shared__ ushort Asl[2][GBM][GBK];   // 16 KB
    __shared__ ushort Bsl[2][GBN][GBK];   // 32 KB
    const int id = blockIdx.x;
    const int k8 = id >> 3;
    const int r8 = id & 7;
    const int p = (k8 >> 1) * 8 + r8;
    const int bnk = k8 & 1;
    if (p >= NBL) return;
    const int bm = p * GBM;
    const int bn = bnk * GBN;
    const int tid = threadIdx.x;
    const int lane = tid & 63;
    const int wid = tid >> 6;
    const int wm = wid >> 1, wn = wid & 1;
    const int l15 = lane & 15, l16 = lane >> 4;

    const int lrow = lane >> 3;
    const int lcolb = 16 * ((lane & 7) ^ lrow);
    const int arow = tid >> 2;
    const int acol = (tid & 3) * 16;
    int agrow = bm + arow; if (agrow >= M) agrow = M - 1;
    const int awoff0 = (acol * 2) ^ ((arow & 7) << 4);
    const int awoff1 = (acol * 2 + 16) ^ ((arow & 7) << 4);

    f32x4 acc[2][4] = {};
    const int nt = K / GBK;

    float4 fa0, fa1, fa2, fa3;
    auto LOADA = [&](int t) {
        const float4* ap = reinterpret_cast<const float4*>(
            &A[(size_t)agrow * K + t * GBK + acol]);
        fa0 = ap[0]; fa1 = ap[1]; fa2 = ap[2]; fa3 = ap[3];
    };
    auto WRITEA = [&](int buf) {
        ushort t16[16];
        t16[0]  = f2b(fa0.x); t16[1]  = f2b(fa0.y); t16[2]  = f2b(fa0.z); t16[3]  = f2b(fa0.w);
        t16[4]  = f2b(fa1.x); t16[5]  = f2b(fa1.y); t16[6]  = f2b(fa1.z); t16[7]  = f2b(fa1.w);
        t16[8]  = f2b(fa2.x); t16[9]  = f2b(fa2.y); t16[10] = f2b(fa2.z); t16[11] = f2b(fa2.w);
        t16[12] = f2b(fa3.x); t16[13] = f2b(fa3.y); t16[14] = f2b(fa3.z); t16[15] = f2b(fa3.w);
        char* base = (char*)&Asl[buf][arow][0];
        *reinterpret_cast<uint4*>(base + awoff0) = *reinterpret_cast<uint4*>(&t16[0]);
        *reinterpret_cast<uint4*>(base + awoff1) = *reinterpret_cast<uint4*>(&t16[8]);
    };
    auto STAGEB = [&](int buf, int t) {
        const int k0 = t * GBK;
        #pragma unroll
        for (int c = 0; c < 4; c++) {
            int chunk = wid * 4 + c;
            int grow = bn + chunk * 8 + lrow;
            const char* src = (const char*)&BT[(size_t)grow * K + k0] + lcolb;
            GLOAD16(src, &Bsl[buf][chunk * 8][0]);
        }
    };

    LOADA(0);
    STAGEB(0, 0);
    WRITEA(0);
    __syncthreads();

    for (int t = 0; t < nt; t++) {
        const int cur = t & 1;
        if (t + 1 < nt) { LOADA(t + 1); STAGEB(cur ^ 1, t + 1); }
        #pragma unroll
        for (int ks = 0; ks < 2; ks++) {
            bf16x8 afr[2], bfr[4];
            #pragma unroll
            for (int i = 0; i < 2; i++) {
                int r = wm * 32 + i * 16 + l15;
                int cb = (ks * 64 + l16 * 16) ^ ((r & 7) << 4);
                afr[i] = *reinterpret_cast<const bf16x8*>((const char*)&Asl[cur][r][0] + cb);
            }
            #pragma unroll
            for (int j = 0; j < 4; j++) {
                int r = wn * 64 + j * 16 + l15;
                int cb = (ks * 64 + l16 * 16) ^ ((r & 7) << 4);
                bfr[j] = *reinterpret_cast<const bf16x8*>((const char*)&Bsl[cur][r][0] + cb);
            }
            #pragma unroll
            for (int i = 0; i < 2; i++)
                #pragma unroll
                for (int j = 0; j < 4; j++)
                    acc[i][j] = __builtin_amdgcn_mfma_f32_16x16x32_bf16(afr[i], bfr[j], acc[i][j], 0, 0, 0);
        }
        if (t + 1 < nt) WRITEA(cur ^ 1);
        __syncthreads();
    }

    #pragma unroll
    for (int i = 0; i < 2; i++) {
        #pragma unroll
        for (int r = 0; r < 4; r++) {
            int grow = bm + wm * 32 + i * 16 + l16 * 4 + r;
            if (grow < M) {
                #pragma unroll
                for (int j = 0; j < 4; j++)
                    C[(size_t)grow * Hn + bn + wn * 64 + j * 16 + l15] = f2b(acc[i][j][r]);
            }
        }
    }
}

// ---------------- bf16 GEMM (layers 2/3): 2-phase double-buffered prefetch ----------------

__global__ __launch_bounds__(256) void k_gemm_bf(
    const ushort* __restrict__ A, const ushort* __restrict__ BT,
    ushort* __restrict__ C, int M, int K, int NBL)
{
    __shared__ ushort Asl[2][GBM][GBK];
    __shared__ ushort Bsl[2][GBN][GBK];
    const int id = blockIdx.x;
    const int k8 = id >> 3;
    const int r8 = id & 7;
    const int p = (k8 >> 1) * 8 + r8;
    const int bnk = k8 & 1;
    if (p >= NBL) return;
    const int bm = p * GBM;
    const int bn = bnk * GBN;
    const int tid = threadIdx.x;
    const int lane = tid & 63;
    const int wid = tid >> 6;
    const int wm = wid >> 1, wn = wid & 1;
    const int l15 = lane & 15, l16 = lane >> 4;

    const int lrow = lane >> 3;
    const int lcolb = 16 * ((lane & 7) ^ lrow);

    f32x4 acc[2][4] = {};
    const int nt = K / GBK;

    auto STAGE = [&](int buf, int t) {
        const int k0 = t * GBK;
        #pragma unroll
        for (int c = 0; c < 2; c++) {
            int chunk = wid * 2 + c;
            int grow = bm + chunk * 8 + lrow;
            if (grow >= M) grow = M - 1;
            const char* src = (const char*)&A[(size_t)grow * K + k0] + lcolb;
            GLOAD16(src, &Asl[buf][chunk * 8][0]);
        }
        #pragma unroll
        for (int c = 0; c < 4; c++) {
            int chunk = wid * 4 + c;
            int grow = bn + chunk * 8 + lrow;
            const char* src = (const char*)&BT[(size_t)grow * K + k0] + lcolb;
            GLOAD16(src, &Bsl[buf][chunk * 8][0]);
        }
    };

    STAGE(0, 0);
    __syncthreads();

    for (int t = 0; t < nt; t++) {
        const int cur = t & 1;
        if (t + 1 < nt) STAGE(cur ^ 1, t + 1);
        #pragma unroll
        for (int ks = 0; ks < 2; ks++) {
            bf16x8 afr[2], bfr[4];
            #pragma unroll
            for (int i = 0; i < 2; i++) {
                int r = wm * 32 + i * 16 + l15;
                int cb = (ks * 64 + l16 * 16) ^ ((r & 7) << 4);
                afr[i] = *reinterpret_cast<const bf16x8*>((const char*)&Asl[cur][r][0] + cb);
            }
            #pragma unroll
            for (int j = 0; j < 4; j++) {
                int r = wn * 64 + j * 16 + l15;
                int cb = (ks * 64 + l16 * 16) ^ ((r & 7) << 4);
                bfr[j] = *reinterpret_cast<const bf16x8*>((const char*)&Bsl[cur][r][0] + cb);
            }
            #pragma unroll
            for (int i = 0; i < 2; i++)
                #pragma unroll
                for (int j = 0; j < 4; j++)
                    acc[i][j] = __builtin_amdgcn_mfma_f32_16x16x32_bf16(afr[i], bfr[j], acc[i][j], 0, 0, 0);
        }
        __syncthreads();
    }

    #pragma unroll
    for (int i = 0; i < 2; i++) {
        #pragma unroll
        for (int r = 0; r < 4; r++) {
            int grow = bm + wm * 32 + i * 16 + l16 * 4 + r;
            if (grow < M) {
                #pragma unroll
                for (int j = 0; j < 4; j++)
                    C[(size_t)grow * Hn + bn + wn * 64 + j * 16 + l15] = f2b(acc[i][j][r]);
            }
        }
    }
}

// ---------------- aggregation: half-wave per node, 4-deep ILP gather ----------------

__device__ __forceinline__ void agg_accum(float* acc, float w, const uint4& v) {
    unsigned int u;
    u = v.x; acc[0] += w * b2f((ushort)u); acc[1] += w * b2f((ushort)(u >> 16));
    u = v.y; acc[2] += w * b2f((ushort)u); acc[3] += w * b2f((ushort)(u >> 16));
    u = v.z; acc[4] += w * b2f((ushort)u); acc[5] += w * b2f((ushort)(u >> 16));
    u = v.w; acc[6] += w * b2f((ushort)u); acc[7] += w * b2f((ushort)(u >> 16));
}

__global__ __launch_bounds__(256) void k_agg(const ushort* __restrict__ xw,
                                             const int* __restrict__ offsets,
                                             const int* __restrict__ csr_row,
                                             const float* __restrict__ csr_w,
                                             const float* __restrict__ dinv2,
                                             const float* __restrict__ bias,
                                             const float* __restrict__ bv,
                                             ushort* __restrict__ outp, int do_relu) {
    int node = blockIdx.x * 8 + (threadIdx.x >> 5);
    int l32 = threadIdx.x & 31;
    int s = offsets[node], e = offsets[node + 1];
    const uint4* xw4 = reinterpret_cast<const uint4*>(xw);

    float acc[8] = {};
    float wsum = 0.f;
    int k = s;
    for (; k + 4 <= e; k += 4) {
        int r0 = csr_row[k],     r1 = csr_row[k + 1];
        int r2 = csr_row[k + 2], r3 = csr_row[k + 3];
        float w0 = csr_w[k],     w1 = csr_w[k + 1];
        float w2 = csr_w[k + 2], w3 = csr_w[k + 3];
        uint4 v0 = xw4[(size_t)r0 * 32 + l32];
        uint4 v1 = xw4[(size_t)r1 * 32 + l32];
        uint4 v2 = xw4[(size_t)r2 * 32 + l32];
        uint4 v3 = xw4[(size_t)r3 * 32 + l32];
        wsum += (w0 + w1) + (w2 + w3);
        agg_accum(acc, w0, v0);
        agg_accum(acc, w1, v1);
        agg_accum(acc, w2, v2);
        agg_accum(acc, w3, v3);
    }
    for (; k < e; k++) {
        int r = csr_row[k];
        float w = csr_w[k];
        uint4 v = xw4[(size_t)r * 32 + l32];
        wsum += w;
        agg_accum(acc, w, v);
    }
    float d2 = dinv2[node];
    wsum += d2;
    uint4 vs = xw4[(size_t)node * 32 + l32];
    agg_accum(acc, d2, vs);

    const float4* bp = reinterpret_cast<const float4*>(&bias[l32 * 8]);
    float4 bb0 = bp[0], bb1 = bp[1];
    acc[0] += bb0.x; acc[1] += bb0.y; acc[2] += bb0.z; acc[3] += bb0.w;
    acc[4] += bb1.x; acc[5] += bb1.y; acc[6] += bb1.z; acc[7] += bb1.w;
    if (bv) {
        const float4* vp = reinterpret_cast<const float4*>(&bv[l32 * 8]);
        float4 bv0 = vp[0], bv1 = vp[1];
        acc[0] += wsum * bv0.x; acc[1] += wsum * bv0.y;
        acc[2] += wsum * bv0.z; acc[3] += wsum * bv0.w;
        acc[4] += wsum * bv1.x; acc[5] += wsum * bv1.y;
        acc[6] += wsum * bv1.z; acc[7] += wsum * bv1.w;
    }
    if (do_relu) {
        #pragma unroll
        for (int q = 0; q < 8; q++) acc[q] = fmaxf(acc[q], 0.f);
    }
    uint4 o;
    o.x = (unsigned int)f2b(acc[0]) | ((unsigned int)f2b(acc[1]) << 16);
    o.y = (unsigned int)f2b(acc[2]) | ((unsigned int)f2b(acc[3]) << 16);
    o.z = (unsigned int)f2b(acc[4]) | ((unsigned int)f2b(acc[5]) << 16);
    o.w = (unsigned int)f2b(acc[6]) | ((unsigned int)f2b(acc[7]) << 16);
    reinterpret_cast<uint4*>(outp)[(size_t)node * 32 + l32] = o;
}

// ---------------- batch-norm stats (partial + reduce; final fused into consumers) ----------------

__global__ __launch_bounds__(256) void k_bnpart(const ushort* __restrict__ h,
                                                float* __restrict__ partial) {
    int f = threadIdx.x;
    int blk = blockIdx.x;
    float s = 0.0f, ss = 0.0f;
    for (int i = blk; i < Nn; i += BNB) {
        float v = b2f(h[(size_t)i * Hn + f]);
        s += v;
        ss += v * v;
    }
    partial[(size_t)blk * 512 + f] = s;
    partial[(size_t)blk * 512 + 256 + f] = ss;
}

__global__ __launch_bounds__(256) void k_bnred(const float* __restrict__ partial,
                                               float* __restrict__ p2) {
    int f = threadIdx.x;
    int b = blockIdx.x;
    int b0 = b * 64;
    float s = 0.0f, ss = 0.0f;
    for (int j = 0; j < 64; j++) {
        const float* p = &partial[(size_t)(b0 + j) * 512];
        s += p[f];
        ss += p[256 + f];
    }
    p2[b * 512 + f] = s;
    p2[b * 512 + 256 + f] = ss;
}

// ---------------- pooling (BN-final fused) ----------------

#define PCH 32

__global__ __launch_bounds__(256) void k_pool2(const ushort* __restrict__ h,
                                               const int* __restrict__ gstart,
                                               const float* __restrict__ p2,
                                               const float* __restrict__ g3,
                                               const float* __restrict__ be3,
                                               float* __restrict__ pooled) {
    int g = blockIdx.x;
    int chunk = blockIdx.y;
    int f = threadIdx.x;
    int s = gstart[g], e = gstart[g + 1];
    int len = e - s;
    if (len <= 0) return;
    int per = (len + PCH - 1) / PCH;
    int cs = s + chunk * per;
    int ce = cs + per; if (ce > e) ce = e;
    if (cs >= ce) return;
    float sc, sh;
    bn_from_p2(p2, g3, be3, f, sc, sh);
    float acc = 0.0f;
    for (int i = cs; i < ce; i++)
        acc += b2f(h[(size_t)i * Hn + f]) * sc + sh;
    atomicAdd(&pooled[g * Hn + f], acc);
}

// ---------------- head: fc1 partials (no atomics) + finish ----------------

__global__ __launch_bounds__(256) void k_head1part(const float* __restrict__ seq_emb,
                                                   const float* __restrict__ fc1_w,
                                                   float* __restrict__ hpart) {
    int g = blockIdx.x;
    int kc = blockIdx.y;
    int j = threadIdx.x;
    const float* se = &seq_emb[(size_t)g * DINn + kc * 128];
    const float* w = &fc1_w[(size_t)kc * 128 * Hn + j];
    float acc = 0.0f;
    #pragma unroll 8
    for (int k = 0; k < 128; k++)
        acc += se[k] * w[(size_t)k * Hn];
    hpart[((size_t)g * 10 + kc) * Hn + j] = acc;
}

__global__ __launch_bounds__(256) void k_head2f(const float* __restrict__ hpart,
                                                const float* __restrict__ fc1_b,
                                                const float* __restrict__ pooled,
                                                const int* __restrict__ gstart,
                                                const float* __restrict__ lin_w,
                                                const float* __restrict__ lin_b,
                                                float* __restrict__ out) {
    __shared__ float pf[Hn];
    int g = blockIdx.x;
    int half = blockIdx.y;
    int j = threadIdx.x;
    float s = fc1_b[j];
    #pragma unroll
    for (int kc = 0; kc < 10; kc++)
        s += hpart[((size_t)g * 10 + kc) * Hn + j];
    float cntf = fmaxf((float)(gstart[g + 1] - gstart[g]), 1.0f);
    pf[j] = pooled[g * Hn + j] / cntf + s;
    __syncthreads();
    int c = half * 250 + j;
    if (j < 250) {
        float a2 = lin_b[c];
        #pragma unroll 8
        for (int k = 0; k < Hn; k++)
            a2 += pf[k] * lin_w[(size_t)k * Cn + c];
        out[g * Cn + c] = 1.0f / (1.0f + expf(-a2));
    }
}

// ---------------- launch ----------------

extern "C" void kernel_launch(void* const* d_in, const int* in_sizes, int n_in,
                              void* d_out, int out_size, void* d_ws, size_t ws_size,
                              hipStream_t stream) {
    const float* x        = (const float*)d_in[0];
    const int*   eidx     = (const int*)d_in[1];
    const float* eattr    = (const float*)d_in[2];
    const int*   batch    = (const int*)d_in[3];
    const float* seq_emb  = (const float*)d_in[4];
    const float* W1 = (const float*)d_in[5];
    const float* b1 = (const float*)d_in[6];
    const float* g1 = (const float*)d_in[7];
    const float* be1 = (const float*)d_in[8];
    const float* W2 = (const float*)d_in[9];
    const float* b2 = (const float*)d_in[10];
    const float* g2 = (const float*)d_in[11];
    const float* be2 = (const float*)d_in[12];
    const float* W3 = (const float*)d_in[13];
    const float* b3 = (const float*)d_in[14];
    const float* g3 = (const float*)d_in[15];
    const float* be3 = (const float*)d_in[16];
    const float* fc1_w = (const float*)d_in[17];
    const float* fc1_b = (const float*)d_in[18];
    const float* lin_w = (const float*)d_in[19];
    const float* lin_b = (const float*)d_in[20];
    float* out = (float*)d_out;

    const int* row = eidx;
    const int* col = eidx + En;

    char* ws = (char*)d_ws;
    size_t off = 0;
    auto alloc = [&](size_t bytes) -> char* {
        char* p = ws + off;
        off += (bytes + 255) & ~(size_t)255;
        return p;
    };
    ushort* xwb    = (ushort*)alloc((size_t)Nn * Hn * 2);
    ushort* hb     = (ushort*)alloc((size_t)Nn * Hn * 2);
    // ---- zero-init region (contiguous, one memset) ----
    char*  zbase   = ws + off;
    float* deg     = (float*)alloc(Nn * 4);
    int*   counts  = (int*)alloc(Nn * 4);
    float* bvA     = (float*)alloc(Hn * 4);
    float* bvB     = (float*)alloc(Hn * 4);
    float* pooled  = (float*)alloc(Gn * Hn * 4);
    size_t zspan   = (size_t)((ws + off) - zbase);
    // ---- rest ----
    float* dinv    = (float*)alloc(Nn * 4);
    float* dinv2   = (float*)alloc(Nn * 4);
    int*   offsets = (int*)alloc((Nn + 1) * 4);
    int*   cursor  = (int*)alloc(Nn * 4);
    int*   excl    = (int*)alloc(Nn * 4);
    int*   blocksum= (int*)alloc(SNB * 4);
    int*   blockoff= (int*)alloc(SNB * 4);
    int*   csr_row = (int*)alloc(En * 4);
    float* csr_w   = (float*)alloc(En * 4);
    int*   gstart  = (int*)alloc((Gn + 1) * 4);
    float* partial = (float*)alloc((size_t)BNB * 512 * 4);
    float* p2      = (float*)alloc(16 * 512 * 4);
    float* hpart   = (float*)alloc((size_t)Gn * 10 * Hn * 4);
    ushort* W1T    = (ushort*)alloc((size_t)Hn * DINn * 2);
    ushort* W2T    = (ushort*)alloc((size_t)Hn * Hn * 2);
    ushort* W3T    = (ushort*)alloc((size_t)Hn * Hn * 2);

    const int TB = 256;
    const int EB = (En + TB - 1) / TB;

    // ---- prep ----
    hipMemsetAsync(zbase, 0, zspan, stream);
    k_degcnt<<<EB, TB, 0, stream>>>(col, eattr, deg, counts);
    k_scanA<<<SNB, SCB, 0, stream>>>(counts, deg, excl, blocksum, dinv, dinv2);
    k_scanB<<<1, 128, 0, stream>>>(blocksum, blockoff, offsets);
    k_scanC<<<SNB, SCB, 0, stream>>>(excl, blockoff, batch, offsets, cursor, gstart);
    k_fill2<<<EB, TB, 0, stream>>>(row, col, eattr, dinv, cursor, csr_row, csr_w);
    k_wt<<<dim3(DINn / 32, Hn / 32), dim3(32, 8), 0, stream>>>(W1, W1T, DINn);

    // XCD-pair-swizzled 1-D GEMM grid
    const int NBL = (Nn + GBM - 1) / GBM;           // 313
    const int GGRID = ((NBL * 2 + 15) / 16) * 16;   // 640
    const int AGB = Nn / 8;

    // ---- layer 1 (f32 A, fused convert) ----
    k_gemm_f32a<<<GGRID, 256, 0, stream>>>(x, W1T, xwb, Nn, DINn, NBL);
    k_agg<<<AGB, 256, 0, stream>>>(xwb, offsets, csr_row, csr_w, dinv2, b1, nullptr, hb, 1);
    k_bnpart<<<BNB, Hn, 0, stream>>>(hb, partial);
    k_bnred<<<16, Hn, 0, stream>>>(partial, p2);

    // ---- layer 2 (BN1 final fused into wtb) ----
    k_wtb<<<dim3(Hn / 32, Hn / 32), dim3(32, 8), 0, stream>>>(W2, p2, g1, be1, W2T, bvA);
    k_gemm_bf<<<GGRID, 256, 0, stream>>>(hb, W2T, xwb, Nn, Hn, NBL);
    k_agg<<<AGB, 256, 0, stream>>>(xwb, offsets, csr_row, csr_w, dinv2, b2, bvA, hb, 1);
    k_bnpart<<<BNB, Hn, 0, stream>>>(hb, partial);
    k_bnred<<<16, Hn, 0, stream>>>(partial, p2);

    // ---- layer 3 (BN2 final fused into wtb) ----
    k_wtb<<<dim3(Hn / 32, Hn / 32), dim3(32, 8), 0, stream>>>(W3, p2, g2, be2, W3T, bvB);
    k_gemm_bf<<<GGRID, 256, 0, stream>>>(hb, W3T, xwb, Nn, Hn, NBL);
    k_agg<<<AGB, 256, 0, stream>>>(xwb, offsets, csr_row, csr_w, dinv2, b3, bvB, hb, 0);
    k_bnpart<<<BNB, Hn, 0, stream>>>(hb, partial);
    k_bnred<<<16, Hn, 0, stream>>>(partial, p2);

    // ---- pooling (BN3 final fused) + head ----
    k_pool2<<<dim3(Gn, PCH), Hn, 0, stream>>>(hb, gstart, p2, g3, be3, pooled);
    k_head1part<<<dim3(Gn, 10), Hn, 0, stream>>>(seq_emb, fc1_w, hpart);
    k_head2f<<<dim3(Gn, 2), Hn, 0, stream>>>(hpart, fc1_b, pooled, gstart, lin_w, lin_b, out);
}